// Round 4
// baseline (765.364 us; speedup 1.0000x reference)
//
#include <hip/hip_runtime.h>
#include <stdint.h>

#define S_ 256
#define T_ 64
#define B_ 8
#define H_ 768
#define V_ 50257
#define R_ 512      // T*B
#define VP_ 50304   // V padded to multiple of 128 (= 393*128)
#define NBLK_ 393   // VP_/128
#define NBP_ 400    // padded NBLK stride

typedef __attribute__((ext_vector_type(8))) short short8;
typedef __attribute__((ext_vector_type(4))) float float4v;

__device__ __forceinline__ float bf2f(unsigned short u) {
  union { unsigned int i; float f; } x; x.i = ((unsigned int)u) << 16; return x.f;
}
__device__ __forceinline__ short f2bf(float f) {
  union { float f; unsigned int i; } x; x.f = f;
  unsigned int u = x.i;
  unsigned int r = u + 0x7fffu + ((u >> 16) & 1u);   // RNE
  return (short)(r >> 16);
}
// tanh(x) = 1 - 2/(e^{2x}+1), e^{2x} = 2^{2x*log2e}. Branch-free, saturates
// correctly at +-inf.
__device__ __forceinline__ float tanh_fast(float x) {
  float e = __builtin_amdgcn_exp2f(2.885390082f * x);
  float r = __builtin_amdgcn_rcpf(e + 1.f);
  return fmaf(-2.f, r, 1.f);
}
// async global->LDS, 16B per lane; LDS dest must be wave-uniform base + lane*16
__device__ __forceinline__ void gload16(const short* g, short* l) {
  __builtin_amdgcn_global_load_lds(
      (const __attribute__((address_space(1))) unsigned int*)g,
      (__attribute__((address_space(3))) unsigned int*)l, 16, 0, 0);
}
// swizzled LDS short-offset for a [128][64]-short tile: row r, col c (shorts, mult of 8)
__device__ __forceinline__ int swz(int r, int c) {
  return r * 64 + (c ^ ((r & 7) * 8));
}

// ---------------- 1. fp32 -> bf16 conversions (x4 vectorized) + zero rowsums ----------------
// grid 1920: (R_*H_ + S_*B_*H_)/4/256 exactly.
__global__ __launch_bounds__(256) void cvt_kernel(const float* __restrict__ dec,
                                                  const float* __restrict__ enc,
                                                  short* __restrict__ dec16,
                                                  short* __restrict__ enc16, float* rowsums) {
  int tid = blockIdx.x * 256 + threadIdx.x;
  if (tid < R_) rowsums[tid] = 0.f;
  const int nd4 = R_ * H_ / 4;            // 98304
  const float4v* src;
  short* dst;
  int off;
  if (tid < nd4) { src = (const float4v*)dec; dst = dec16; off = tid; }
  else           { src = (const float4v*)enc; dst = enc16; off = tid - nd4; }
  float4v v = src[off];
  union { short s[4]; unsigned long long u; } pk;
  pk.s[0] = f2bf(v[0]); pk.s[1] = f2bf(v[1]); pk.s[2] = f2bf(v[2]); pk.s[3] = f2bf(v[3]);
  *(unsigned long long*)&dst[(size_t)off * 4] = pk.u;
}

// ---------------- 2. W_attn [1536][768] -> WAT16 [768][1536] (transpose+cvt) ----------------
__global__ __launch_bounds__(256) void twat_kernel(const float* in, short* out) {
  __shared__ float tile[64][65];
  int n0 = blockIdx.x * 64;   // over 768 (out rows)
  int k0 = blockIdx.y * 64;   // over 1536
  int t = threadIdx.x;
  int c = t & 63, rsub = t >> 6;
#pragma unroll
  for (int i = 0; i < 16; ++i) {
    int r = i * 4 + rsub;
    tile[r][c] = in[(size_t)(k0 + r) * 768 + n0 + c];
  }
  __syncthreads();
#pragma unroll
  for (int i = 0; i < 16; ++i) {
    int nn = i * 4 + rsub;
    out[(size_t)(n0 + nn) * 1536 + k0 + c] = f2bf(tile[c][nn]);
  }
}

// ---------------- 2b. W_gen [768][V] fp32 -> WT16 [VP][768] bf16 (transpose+cvt) ------------
// Sequential-burst restructure: block = 32 k-rows x 512 v-cols. Per row the block's
// aggregate read stream is 2KB sequential (4x longer bursts than before) and rows are
// visited in ascending order -> DRAM page-friendly. bf16 conversion happens BEFORE LDS
// (tile is bf16, 33.4KB). Phase-2 transposed read is conflict-free (stride 522 shorts:
// banks = kq*8 + vv/2, 32 distinct, 2-way free). grid (99, 24).
__global__ __launch_bounds__(256) void cvt_wt_kernel(const float* __restrict__ in,
                                                     short* __restrict__ out) {
  __shared__ short tile[32][522];
  int v0 = blockIdx.x * 512, k0 = blockIdx.y * 32;
  int t = threadIdx.x;
#pragma unroll
  for (int g = 0; g < 4; ++g) {
    float vals[16];
#pragma unroll
    for (int i = 0; i < 16; ++i) {
      int q = (g * 16 + i) * 256 + t;
      int r = q >> 9, c = q & 511;
      int v = v0 + c;
      vals[i] = (v < V_) ? in[(size_t)(k0 + r) * V_ + v] : 0.f;
    }
#pragma unroll
    for (int i = 0; i < 16; ++i) {
      int q = (g * 16 + i) * 256 + t;
      tile[q >> 9][q & 511] = f2bf(vals[i]);
    }
  }
  __syncthreads();
  int kq = t & 3, vs = t >> 2;
#pragma unroll
  for (int p = 0; p < 8; ++p) {
    int vv = p * 64 + vs;
    int vrow = v0 + vv;
    if (vrow < VP_) {
      union { short s[8]; short8 v8; } pk;
#pragma unroll
      for (int j = 0; j < 8; ++j) pk.s[j] = tile[kq * 8 + j][vv];
      *(short8*)&out[(size_t)vrow * 768 + k0 + kq * 8] = pk.v8;
    }
  }
}

// ---------------- 3/4. proj GEMM (vocab-style pipeline): C[M][768] = A @ W + bias ----------
__global__ __launch_bounds__(256, 3) void gemm_proj(const short* __restrict__ A,
                                                    const short* __restrict__ BT,
                                                    int koff, const float* __restrict__ bias,
                                                    float* __restrict__ C) {
  __shared__ __align__(16) short Bl[2][128 * 64];
  int t = threadIdx.x;
  int w = t >> 6, l = t & 63;
  int n0 = blockIdx.x * 128;
  int m0 = blockIdx.y * 128;
  int wm = w >> 1, wn = w & 1;
  int lm = l & 15, lq = l >> 4;
  int srow = t >> 3;
  int scol = ((t & 7) ^ (srow & 7)) * 8;

  float4v acc[4][4];
#pragma unroll
  for (int i = 0; i < 4; ++i)
#pragma unroll
    for (int j = 0; j < 4; ++j) acc[i][j] = float4v{0.f, 0.f, 0.f, 0.f};

  const short* bS = BT + (size_t)(n0 + srow) * 1536 + koff + scol;
  const short* aR = A + (size_t)(m0 + wm * 64 + lm) * 768 + lq * 8;

  auto STAGE = [&](int buf, int kk) {
#pragma unroll
    for (int i = 0; i < 4; ++i)
      gload16(bS + (size_t)i * 32 * 1536 + kk, &Bl[buf][(i * 32 + w * 8) * 64]);
  };

  STAGE(0, 0);
#pragma unroll 1
  for (int kt = 0; kt < 12; ++kt) {
    int cb = kt & 1;
    int kk = kt * 64;
    short8 af[2][4];
#pragma unroll
    for (int ks = 0; ks < 2; ++ks)
#pragma unroll
      for (int mt = 0; mt < 4; ++mt)
        af[ks][mt] = *(const short8*)&aR[(size_t)mt * 16 * 768 + kk + ks * 32];
    if (kt < 11) {
      STAGE(cb ^ 1, kk + 64);
      asm volatile("s_waitcnt vmcnt(12)" ::: "memory");
    } else {
      asm volatile("s_waitcnt vmcnt(8)" ::: "memory");
    }
    __builtin_amdgcn_s_barrier();

    short8 bfr[2][4];
#pragma unroll
    for (int ks = 0; ks < 2; ++ks)
#pragma unroll
      for (int nt = 0; nt < 4; ++nt)
        bfr[ks][nt] = *(const short8*)&Bl[cb][swz(wn * 64 + nt * 16 + lm, ks * 32 + lq * 8)];
    asm volatile("s_waitcnt lgkmcnt(0)" ::: "memory");
    if (kt < 11)
      asm volatile("s_waitcnt vmcnt(4)" ::: "memory");
    else
      asm volatile("s_waitcnt vmcnt(0)" ::: "memory");
    __builtin_amdgcn_s_barrier();

#pragma unroll
    for (int ks = 0; ks < 2; ++ks)
#pragma unroll
      for (int mt = 0; mt < 4; ++mt)
#pragma unroll
        for (int nt = 0; nt < 4; ++nt)
          acc[mt][nt] = __builtin_amdgcn_mfma_f32_16x16x32_bf16(af[ks][mt], bfr[ks][nt],
                                                                acc[mt][nt], 0, 0, 0);
  }

  int q4 = lq * 4, ln = lm;
#pragma unroll
  for (int nt = 0; nt < 4; ++nt) {
    int c = n0 + wn * 64 + nt * 16 + ln;
    float bv = bias ? bias[c] : 0.f;
#pragma unroll
    for (int mt = 0; mt < 4; ++mt)
#pragma unroll
      for (int r = 0; r < 4; ++r)
        C[(size_t)(m0 + wm * 64 + mt * 16 + q4 + r) * 768 + c] = acc[mt][nt][r] + bv;
  }
}

// ---------------- 5. energy ----------------
__global__ __launch_bounds__(256) void energy_kernel(const float* __restrict__ dproj,
                                                     const float* __restrict__ eproj,
                                                     const float* vattn, const float* bv,
                                                     float* scores) {
  __shared__ float dch[16][65];
  __shared__ float ech[16][65];
  __shared__ float vch[64];
  int s0 = blockIdx.x * 16;
  int b  = blockIdx.y;
  int t0 = blockIdx.z * 16;
  int t = threadIdx.x;
  int sl = t & 15, tl = t >> 4;
  float acc = 0.f;
  for (int hc = 0; hc < 768; hc += 64) {
#pragma unroll
    for (int i = 0; i < 4; ++i) {
      int idx = i * 256 + t;
      int rr = idx >> 6, cc = idx & 63;
      dch[rr][cc] = dproj[(size_t)((t0 + rr) * 8 + b) * 768 + hc + cc];
      ech[rr][cc] = eproj[(size_t)((s0 + rr) * 8 + b) * 768 + hc + cc];
    }
    if (t < 64) vch[t] = vattn[hc + t];
    __syncthreads();
#pragma unroll 8
    for (int hh = 0; hh < 64; ++hh) {
      float x = dch[tl][hh] + ech[sl][hh];
      acc = fmaf(tanh_fast(x), vch[hh], acc);
    }
    __syncthreads();
  }
  scores[(size_t)((t0 + tl) * 8 + b) * 256 + s0 + sl] = acc + bv[0];
}

// ---------------- 6. masked softmax over s per row r ----------------
__global__ __launch_bounds__(256) void softmax_kernel(const float* scores, const int* sid, float* P) {
  __shared__ float red[256];
  int r = blockIdx.x, t = threadIdx.x, b = r & 7;
  float v = scores[(size_t)r * 256 + t];
  if (sid[t * 8 + b] == 0) v = -1e10f;
  red[t] = v;
  __syncthreads();
  for (int s = 128; s > 0; s >>= 1) {
    if (t < s) red[t] = fmaxf(red[t], red[t + s]);
    __syncthreads();
  }
  float m = red[0];
  __syncthreads();
  float e = __expf(v - m);
  red[t] = e;
  __syncthreads();
  for (int s = 128; s > 0; s >>= 1) {
    if (t < s) red[t] += red[t + s];
    __syncthreads();
  }
  P[(size_t)r * 256 + t] = e * (1.f / red[0]);
}

// ---------------- 7. ctx ----------------
__global__ __launch_bounds__(256) void ctx_kernel(const float* __restrict__ P,
                                                  const float* __restrict__ enc, float* ctx) {
  __shared__ float Pl[16][256];
  int h0 = blockIdx.x * 64;
  int b  = blockIdx.y;
  int tg = blockIdx.z;
  int t = threadIdx.x;
  int hl = t & 63, wv = t >> 6;
#pragma unroll
  for (int i = 0; i < 16; ++i) {
    int idx = i * 256 + t;
    int tt = idx >> 8, s = idx & 255;
    Pl[tt][s] = P[(size_t)((tg * 16 + tt) * 8 + b) * 256 + s];
  }
  __syncthreads();
  float acc[4] = {0.f, 0.f, 0.f, 0.f};
#pragma unroll 4
  for (int s = 0; s < 256; ++s) {
    float e = enc[(size_t)(s * 8 + b) * 768 + h0 + hl];
#pragma unroll
    for (int j = 0; j < 4; ++j)
      acc[j] = fmaf(Pl[wv * 4 + j][s], e, acc[j]);
  }
#pragma unroll
  for (int j = 0; j < 4; ++j)
    ctx[(size_t)((tg * 16 + wv * 4 + j) * 8 + b) * 768 + h0 + hl] = acc[j];
}

// ---------------- 8. p_gen ----------------
__global__ __launch_bounds__(256) void pgen_kernel(const float* dec, const float* ctx,
                                                   const float* tgt, const float* Wp,
                                                   const float* bp, float* pgen) {
  __shared__ float red[256];
  int r = blockIdx.x, t = threadIdx.x;
  float s = 0.f;
  for (int h = t; h < 768; h += 256) {
    s = fmaf(dec[(size_t)r * 768 + h], Wp[h], s);
    s = fmaf(ctx[(size_t)r * 768 + h], Wp[768 + h], s);
    s = fmaf(tgt[(size_t)r * 768 + h], Wp[1536 + h], s);
  }
  red[t] = s;
  __syncthreads();
  for (int st = 128; st > 0; st >>= 1) {
    if (t < st) red[t] += red[t + st];
    __syncthreads();
  }
  if (t == 0) pgen[r] = 1.f / (1.f + __expf(-(red[0] + bp[0])));
}

// ---------------- 9a. vocab GEMM variant A: counted-vmcnt double-buffer pipeline ----------
// Panels 0..196 (788 blocks). Structure identical to round 3.
__global__ __launch_bounds__(256, 3) void gemm_vocab_a(const short* __restrict__ A,
                                                       const short* __restrict__ BT,
                                                       const float* __restrict__ bgen,
                                                       short* __restrict__ E,
                                                       float* __restrict__ prs) {
  __shared__ __align__(16) short Bl[2][128 * 64];   // 2 x 16KB
  int t = threadIdx.x;
  int w = t >> 6, l = t & 63;
  // bijective XCD swizzle: nwg=788 = 8*98+4
  int orig = blockIdx.x;
  int xcd = orig & 7, ix = orig >> 3;
  int wgid = (xcd < 4 ? xcd * 99 : 396 + (xcd - 4) * 98) + ix;
  int nblk = wgid >> 2;
  int n0 = nblk * 128;
  int m0 = (wgid & 3) * 128;
  int wm = w >> 1, wn = w & 1;
  int lm = l & 15, lq = l >> 4;
  int srow = t >> 3;
  int scol = ((t & 7) ^ (srow & 7)) * 8;

  float4v acc[4][4];
#pragma unroll
  for (int i = 0; i < 4; ++i)
#pragma unroll
    for (int j = 0; j < 4; ++j) acc[i][j] = float4v{0.f, 0.f, 0.f, 0.f};

  const short* bS = BT + (size_t)(n0 + srow) * 768 + scol;
  const short* aR = A + (size_t)(m0 + wm * 64 + lm) * 768 + lq * 8;

  auto STAGE = [&](int buf, int kk) {
#pragma unroll
    for (int i = 0; i < 4; ++i)
      gload16(bS + (size_t)i * 32 * 768 + kk, &Bl[buf][(i * 32 + w * 8) * 64]);
  };

  STAGE(0, 0);
#pragma unroll 1
  for (int kt = 0; kt < 12; ++kt) {
    int cb = kt & 1;
    int kk = kt * 64;
    short8 af[2][4];
#pragma unroll
    for (int ks = 0; ks < 2; ++ks)
#pragma unroll
      for (int mt = 0; mt < 4; ++mt)
        af[ks][mt] = *(const short8*)&aR[(size_t)mt * 16 * 768 + kk + ks * 32];
    if (kt < 11) {
      STAGE(cb ^ 1, kk + 64);
      asm volatile("s_waitcnt vmcnt(12)" ::: "memory");
    } else {
      asm volatile("s_waitcnt vmcnt(8)" ::: "memory");
    }
    __builtin_amdgcn_s_barrier();

    short8 bfr[2][4];
#pragma unroll
    for (int ks = 0; ks < 2; ++ks)
#pragma unroll
      for (int nt = 0; nt < 4; ++nt)
        bfr[ks][nt] = *(const short8*)&Bl[cb][swz(wn * 64 + nt * 16 + lm, ks * 32 + lq * 8)];
    asm volatile("s_waitcnt lgkmcnt(0)" ::: "memory");
    if (kt < 11)
      asm volatile("s_waitcnt vmcnt(4)" ::: "memory");
    else
      asm volatile("s_waitcnt vmcnt(0)" ::: "memory");
    __builtin_amdgcn_s_barrier();

#pragma unroll
    for (int ks = 0; ks < 2; ++ks)
#pragma unroll
      for (int mt = 0; mt < 4; ++mt)
#pragma unroll
        for (int nt = 0; nt < 4; ++nt)
          acc[mt][nt] = __builtin_amdgcn_mfma_f32_16x16x32_bf16(af[ks][mt], bfr[ks][nt],
                                                                acc[mt][nt], 0, 0, 0);
  }

  // epilogue
  int q4 = lq * 4, ln = lm;
  float rs[4][4];
#pragma unroll
  for (int i = 0; i < 4; ++i)
#pragma unroll
    for (int j = 0; j < 4; ++j) rs[i][j] = 0.f;
#pragma unroll
  for (int nt = 0; nt < 4; ++nt) {
    int c = n0 + wn * 64 + nt * 16 + ln;
    bool valid = c < V_;
    float bg = valid ? bgen[c] : 0.f;
#pragma unroll
    for (int mt = 0; mt < 4; ++mt)
#pragma unroll
      for (int r = 0; r < 4; ++r) {
        float e = valid ? __expf(acc[mt][nt][r] + bg) : 0.f;
        int row = m0 + wm * 64 + mt * 16 + q4 + r;
        E[(size_t)row * VP_ + c] = f2bf(e);
        rs[mt][r] += e;
      }
  }
  float* red = (float*)Bl;
  if (t < 128) red[t] = 0.f;
  __syncthreads();
#pragma unroll
  for (int mt = 0; mt < 4; ++mt)
#pragma unroll
    for (int r = 0; r < 4; ++r) {
      float v = rs[mt][r];
      v += __shfl_xor(v, 1);
      v += __shfl_xor(v, 2);
      v += __shfl_xor(v, 4);
      v += __shfl_xor(v, 8);
      if (ln == 0) atomicAdd(&red[wm * 64 + mt * 16 + q4 + r], v);
    }
  __syncthreads();
  if (t < 128) prs[(size_t)(m0 + t) * NBP_ + nblk] = red[t];
}

// ---------------- 9b2. vocab GEMM variant B: single-buffer full-drain, high TLP ----------
// Panels 197..392 (784 blocks). 16KB LDS + launch_bounds(256,6) -> ~6-7 resident
// blocks/CU (24-28 waves) vs A's 2-3 blocks. Tests whether vocab's stall is TLP
// starvation (B much faster) or intrinsic (equal).
__global__ __launch_bounds__(256, 6) void gemm_vocab_b(const short* __restrict__ A,
                                                       const short* __restrict__ BT,
                                                       const float* __restrict__ bgen,
                                                       short* __restrict__ E,
                                                       float* __restrict__ prs) {
  __shared__ __align__(16) short Bl[128 * 64];      // 16KB
  int t = threadIdx.x;
  int w = t >> 6, l = t & 63;
  // XCD swizzle: nwg=784 = 8*98 exact
  int orig = blockIdx.x;
  int wgid = (orig & 7) * 98 + (orig >> 3);
  int nblk = 197 + (wgid >> 2);
  int n0 = nblk * 128;
  int m0 = (wgid & 3) * 128;
  int wm = w >> 1, wn = w & 1;
  int lm = l & 15, lq = l >> 4;
  int srow = t >> 3;
  int scol = ((t & 7) ^ (srow & 7)) * 8;

  float4v acc[4][4];
#pragma unroll
  for (int i = 0; i < 4; ++i)
#pragma unroll
    for (int j = 0; j < 4; ++j) acc[i][j] = float4v{0.f, 0.f, 0.f, 0.f};

  const short* bS = BT + (size_t)(n0 + srow) * 768 + scol;
  const short* aR = A + (size_t)(m0 + wm * 64 + lm) * 768 + lq * 8;

#pragma unroll 1
  for (int kt = 0; kt < 12; ++kt) {
    int kk = kt * 64;
    short8 af[2][4];
#pragma unroll
    for (int ks = 0; ks < 2; ++ks)
#pragma unroll
      for (int mt = 0; mt < 4; ++mt)
        af[ks][mt] = *(const short8*)&aR[(size_t)mt * 16 * 768 + kk + ks * 32];
#pragma unroll
    for (int i = 0; i < 4; ++i)
      gload16(bS + (size_t)i * 32 * 768 + kk, &Bl[(i * 32 + w * 8) * 64]);
    asm volatile("s_waitcnt vmcnt(0)" ::: "memory");
    __builtin_amdgcn_s_barrier();

    short8 bfr[2][4];
#pragma unroll
    for (int ks = 0; ks < 2; ++ks)
#pragma unroll
      for (int nt = 0; nt < 4; ++nt)
        bfr[ks][nt] = *(const short8*)&Bl[swz(wn * 64 + nt * 16 + lm, ks * 32 + lq * 8)];
    asm volatile("s_waitcnt lgkmcnt(0)" ::: "memory");
    __builtin_amdgcn_s_barrier();

#pragma unroll
    for (int ks = 0; ks < 2; ++ks)
#pragma unroll
      for (int mt = 0; mt < 4; ++mt)
#pragma unroll
        for (int nt = 0; nt < 4; ++nt)
          acc[mt][nt] = __builtin_amdgcn_mfma_f32_16x16x32_bf16(af[ks][mt], bfr[ks][nt],
                                                                acc[mt][nt], 0, 0, 0);
  }

  // epilogue (identical to A)
  int q4 = lq * 4, ln = lm;
  float rs[4][4];
#pragma unroll
  for (int i = 0; i < 4; ++i)
#pragma unroll
    for (int j = 0; j < 4; ++j) rs[i][j] = 0.f;
#pragma unroll
  for (int nt = 0; nt < 4; ++nt) {
    int c = n0 + wn * 64 + nt * 16 + ln;
    bool valid = c < V_;
    float bg = valid ? bgen[c] : 0.f;
#pragma unroll
    for (int mt = 0; mt < 4; ++mt)
#pragma unroll
      for (int r = 0; r < 4; ++r) {
        float e = valid ? __expf(acc[mt][nt][r] + bg) : 0.f;
        int row = m0 + wm * 64 + mt * 16 + q4 + r;
        E[(size_t)row * VP_ + c] = f2bf(e);
        rs[mt][r] += e;
      }
  }
  float* red = (float*)Bl;
  if (t < 128) red[t] = 0.f;
  __syncthreads();
#pragma unroll
  for (int mt = 0; mt < 4; ++mt)
#pragma unroll
    for (int r = 0; r < 4; ++r) {
      float v = rs[mt][r];
      v += __shfl_xor(v, 1);
      v += __shfl_xor(v, 2);
      v += __shfl_xor(v, 4);
      v += __shfl_xor(v, 8);
      if (ln == 0) atomicAdd(&red[wm * 64 + mt * 16 + q4 + r], v);
    }
  __syncthreads();
  if (t < 128) prs[(size_t)(m0 + t) * NBP_ + nblk] = red[t];
}

// ---------------- 9c. rowsums[r] = sum over nblk of prs[r][nblk] ----------------
__global__ __launch_bounds__(256) void rowsum_reduce(const float* __restrict__ prs,
                                                     float* __restrict__ rowsums) {
  __shared__ float red[256];
  int r = blockIdx.x, t = threadIdx.x;
  float s = prs[(size_t)r * NBP_ + t];
  if (t + 256 < NBLK_) s += prs[(size_t)r * NBP_ + t + 256];
  red[t] = s;
  __syncthreads();
  for (int st = 128; st > 0; st >>= 1) {
    if (t < st) red[t] += red[t + st];
    __syncthreads();
  }
  if (t == 0) rowsums[r] = red[0];
}

// ---------------- 10. final: out = E*pg/Z then scatter-add (chunk-local) ----------------
__global__ __launch_bounds__(256) void final_kernel(const short* __restrict__ E,
                                                    const float* __restrict__ P,
                                                    const float* pgen, const float* rowsums,
                                                    const int* sid, float* __restrict__ out) {
  int r = blockIdx.y, t = threadIdx.x, b = r & 7;
  int lo = blockIdx.x * 2048, hi = lo + 2048;
  float pg = pgen[r];
  float scale = pg / rowsums[r];
  const short* Er = E + (size_t)r * VP_;
  float* outr = out + (size_t)r * V_;
#pragma unroll
  for (int j = 0; j < 8; ++j) {
    int c = lo + j * 256 + t;
    if (c < V_) outr[c] = bf2f((unsigned short)Er[c]) * scale;
  }
  __syncthreads();
  int idx = sid[t * 8 + b];
  if (idx >= lo && idx < hi) {
    float ap = (1.f - pg) * P[(size_t)r * 256 + t];
    atomicAdd(&outr[idx], ap);
  }
}

extern "C" void kernel_launch(void* const* d_in, const int* in_sizes, int n_in,
                              void* d_out, int out_size, void* d_ws, size_t ws_size,
                              hipStream_t stream) {
  const float* enc  = (const float*)d_in[0];
  const float* dec  = (const float*)d_in[1];
  const int*   sid  = (const int*)d_in[2];
  const float* tgt  = (const float*)d_in[3];
  const float* Wat  = (const float*)d_in[4];
  const float* batt = (const float*)d_in[5];
  const float* vatt = (const float*)d_in[6];
  const float* bv   = (const float*)d_in[7];
  const float* Wp   = (const float*)d_in[8];
  const float* bp   = (const float*)d_in[9];
  const float* Wg   = (const float*)d_in[10];
  const float* bg   = (const float*)d_in[11];
  float* out = (float*)d_out;

  char* ws = (char*)d_ws;
  size_t off = 0;
  auto alloc = [&](size_t bytes) -> char* {
    char* p = ws + off;
    off += (bytes + 255) & ~(size_t)255;
    return p;
  };
  short* E16     = (short*)alloc((size_t)R_ * VP_ * 2);     // 51.5 MB
  short* WT16    = (short*)alloc((size_t)VP_ * H_ * 2);     // 77.3 MB
  short* dec16   = (short*)alloc((size_t)R_ * H_ * 2);
  short* enc16   = (short*)alloc((size_t)S_ * B_ * H_ * 2);
  short* WAT16   = (short*)alloc((size_t)H_ * 1536 * 2);
  float* dproj   = (float*)alloc((size_t)R_ * H_ * 4);
  float* eproj   = (float*)alloc((size_t)S_ * B_ * H_ * 4);
  float* scores  = (float*)alloc((size_t)R_ * 256 * 4);
  float* P       = (float*)alloc((size_t)R_ * 256 * 4);
  float* ctx     = (float*)alloc((size_t)R_ * H_ * 4);
  float* pgen    = (float*)alloc(R_ * 4);
  float* rowsums = (float*)alloc(R_ * 4);
  float* prs     = (float*)alloc((size_t)R_ * NBP_ * 4);    // 0.8 MB

  cvt_kernel<<<1920, 256, 0, stream>>>(dec, enc, dec16, enc16, rowsums);
  twat_kernel<<<dim3(12, 24), 256, 0, stream>>>(Wat, WAT16);
  cvt_wt_kernel<<<dim3(99, 24), 256, 0, stream>>>(Wg, WT16);
  gemm_proj<<<dim3(6, 4), 256, 0, stream>>>(dec16, WAT16, 0, nullptr, dproj);
  gemm_proj<<<dim3(6, 16), 256, 0, stream>>>(enc16, WAT16, 768, batt, eproj);
  energy_kernel<<<dim3(16, 8, 4), 256, 0, stream>>>(dproj, eproj, vatt, bv, scores);
  softmax_kernel<<<512, 256, 0, stream>>>(scores, sid, P);
  ctx_kernel<<<dim3(12, 8, 4), 256, 0, stream>>>(P, enc, ctx);
  pgen_kernel<<<512, 256, 0, stream>>>(dec, ctx, tgt, Wp, bp, pgen);
  gemm_vocab_a<<<dim3(788), 256, 0, stream>>>(dec16, WT16, bg, E16, prs);
  gemm_vocab_b<<<dim3(784), 256, 0, stream>>>(dec16, WT16, bg, E16, prs);
  rowsum_reduce<<<512, 256, 0, stream>>>(prs, rowsums);
  final_kernel<<<dim3(25, 512), 256, 0, stream>>>(E16, P, pgen, rowsums, sid, out);
}

// Round 5
// 547.378 us; speedup vs baseline: 1.3982x; 1.3982x over previous
//
#include <hip/hip_runtime.h>
#include <stdint.h>

#define S_ 256
#define T_ 64
#define B_ 8
#define H_ 768
#define V_ 50257
#define R_ 512      // T*B
#define VP_ 50304   // V padded to multiple of 128 (= 393*128)
#define NBLK_ 393   // VP_/128
#define NBP_ 400    // padded NBLK stride

typedef __attribute__((ext_vector_type(8))) short short8;
typedef __attribute__((ext_vector_type(4))) float float4v;

__device__ __forceinline__ float bf2f(unsigned short u) {
  union { unsigned int i; float f; } x; x.i = ((unsigned int)u) << 16; return x.f;
}
__device__ __forceinline__ short f2bf(float f) {
  union { float f; unsigned int i; } x; x.f = f;
  unsigned int u = x.i;
  unsigned int r = u + 0x7fffu + ((u >> 16) & 1u);   // RNE
  return (short)(r >> 16);
}
// tanh(x) = 1 - 2/(e^{2x}+1). Branch-free, saturates correctly.
__device__ __forceinline__ float tanh_fast(float x) {
  float e = __builtin_amdgcn_exp2f(2.885390082f * x);
  float r = __builtin_amdgcn_rcpf(e + 1.f);
  return fmaf(-2.f, r, 1.f);
}
// async global->LDS, 16B per lane; LDS dest must be wave-uniform base + lane*16
__device__ __forceinline__ void gload16(const short* g, short* l) {
  __builtin_amdgcn_global_load_lds(
      (const __attribute__((address_space(1))) unsigned int*)g,
      (__attribute__((address_space(3))) unsigned int*)l, 16, 0, 0);
}
// swizzled LDS short-offset for a [128][64]-short tile: row r, col c (shorts, mult of 8)
__device__ __forceinline__ int swz(int r, int c) {
  return r * 64 + (c ^ ((r & 7) * 8));
}

// ---------------- 1. fp32 -> bf16 conversions (x4 vectorized) + zero rowsums ----------------
__global__ __launch_bounds__(256) void cvt_kernel(const float* __restrict__ dec,
                                                  const float* __restrict__ enc,
                                                  short* __restrict__ dec16,
                                                  short* __restrict__ enc16, float* rowsums) {
  int tid = blockIdx.x * 256 + threadIdx.x;
  if (tid < R_) rowsums[tid] = 0.f;
  const int nd4 = R_ * H_ / 4;            // 98304
  const float4v* src;
  short* dst;
  int off;
  if (tid < nd4) { src = (const float4v*)dec; dst = dec16; off = tid; }
  else           { src = (const float4v*)enc; dst = enc16; off = tid - nd4; }
  float4v v = src[off];
  union { short s[4]; unsigned long long u; } pk;
  pk.s[0] = f2bf(v[0]); pk.s[1] = f2bf(v[1]); pk.s[2] = f2bf(v[2]); pk.s[3] = f2bf(v[3]);
  *(unsigned long long*)&dst[(size_t)off * 4] = pk.u;
}

// ---------------- 2. W_attn [1536][768] -> WAT16 [768][1536] (transpose+cvt) ----------------
__global__ __launch_bounds__(256) void twat_kernel(const float* in, short* out) {
  __shared__ float tile[64][65];
  int n0 = blockIdx.x * 64;   // over 768 (out rows)
  int k0 = blockIdx.y * 64;   // over 1536
  int t = threadIdx.x;
  int c = t & 63, rsub = t >> 6;
#pragma unroll
  for (int i = 0; i < 16; ++i) {
    int r = i * 4 + rsub;
    tile[r][c] = in[(size_t)(k0 + r) * 768 + n0 + c];
  }
  __syncthreads();
#pragma unroll
  for (int i = 0; i < 16; ++i) {
    int nn = i * 4 + rsub;
    out[(size_t)(n0 + nn) * 1536 + k0 + c] = f2bf(tile[c][nn]);
  }
}

// ---------------- 2b. W_gen [768][V] fp32 -> WT16 [VP][768] bf16 (transpose+cvt) ------------
// block = 32 k-rows x 512 v-cols; per-row aggregate read stream is 2KB sequential.
__global__ __launch_bounds__(256) void cvt_wt_kernel(const float* __restrict__ in,
                                                     short* __restrict__ out) {
  __shared__ short tile[32][522];
  int v0 = blockIdx.x * 512, k0 = blockIdx.y * 32;
  int t = threadIdx.x;
#pragma unroll
  for (int g = 0; g < 4; ++g) {
    float vals[16];
#pragma unroll
    for (int i = 0; i < 16; ++i) {
      int q = (g * 16 + i) * 256 + t;
      int r = q >> 9, c = q & 511;
      int v = v0 + c;
      vals[i] = (v < V_) ? in[(size_t)(k0 + r) * V_ + v] : 0.f;
    }
#pragma unroll
    for (int i = 0; i < 16; ++i) {
      int q = (g * 16 + i) * 256 + t;
      tile[q >> 9][q & 511] = f2bf(vals[i]);
    }
  }
  __syncthreads();
  int kq = t & 3, vs = t >> 2;
#pragma unroll
  for (int p = 0; p < 8; ++p) {
    int vv = p * 64 + vs;
    int vrow = v0 + vv;
    if (vrow < VP_) {
      union { short s[8]; short8 v8; } pk;
#pragma unroll
      for (int j = 0; j < 8; ++j) pk.s[j] = tile[kq * 8 + j][vv];
      *(short8*)&out[(size_t)vrow * 768 + k0 + kq * 8] = pk.v8;
    }
  }
}

// ---------------- 3/4. proj GEMM (vocab-style pipeline): C[M][768] = A @ W + bias ----------
__global__ __launch_bounds__(256, 3) void gemm_proj(const short* __restrict__ A,
                                                    const short* __restrict__ BT,
                                                    int koff, const float* __restrict__ bias,
                                                    float* __restrict__ C) {
  __shared__ __align__(16) short Bl[2][128 * 64];
  int t = threadIdx.x;
  int w = t >> 6, l = t & 63;
  int n0 = blockIdx.x * 128;
  int m0 = blockIdx.y * 128;
  int wm = w >> 1, wn = w & 1;
  int lm = l & 15, lq = l >> 4;
  int srow = t >> 3;
  int scol = ((t & 7) ^ (srow & 7)) * 8;

  float4v acc[4][4];
#pragma unroll
  for (int i = 0; i < 4; ++i)
#pragma unroll
    for (int j = 0; j < 4; ++j) acc[i][j] = float4v{0.f, 0.f, 0.f, 0.f};

  const short* bS = BT + (size_t)(n0 + srow) * 1536 + koff + scol;
  const short* aR = A + (size_t)(m0 + wm * 64 + lm) * 768 + lq * 8;

  auto STAGE = [&](int buf, int kk) {
#pragma unroll
    for (int i = 0; i < 4; ++i)
      gload16(bS + (size_t)i * 32 * 1536 + kk, &Bl[buf][(i * 32 + w * 8) * 64]);
  };

  STAGE(0, 0);
#pragma unroll 1
  for (int kt = 0; kt < 12; ++kt) {
    int cb = kt & 1;
    int kk = kt * 64;
    short8 af[2][4];
#pragma unroll
    for (int ks = 0; ks < 2; ++ks)
#pragma unroll
      for (int mt = 0; mt < 4; ++mt)
        af[ks][mt] = *(const short8*)&aR[(size_t)mt * 16 * 768 + kk + ks * 32];
    if (kt < 11) {
      STAGE(cb ^ 1, kk + 64);
      asm volatile("s_waitcnt vmcnt(12)" ::: "memory");
    } else {
      asm volatile("s_waitcnt vmcnt(8)" ::: "memory");
    }
    __builtin_amdgcn_s_barrier();

    short8 bfr[2][4];
#pragma unroll
    for (int ks = 0; ks < 2; ++ks)
#pragma unroll
      for (int nt = 0; nt < 4; ++nt)
        bfr[ks][nt] = *(const short8*)&Bl[cb][swz(wn * 64 + nt * 16 + lm, ks * 32 + lq * 8)];
    asm volatile("s_waitcnt lgkmcnt(0)" ::: "memory");
    if (kt < 11)
      asm volatile("s_waitcnt vmcnt(4)" ::: "memory");
    else
      asm volatile("s_waitcnt vmcnt(0)" ::: "memory");
    __builtin_amdgcn_s_barrier();

#pragma unroll
    for (int ks = 0; ks < 2; ++ks)
#pragma unroll
      for (int mt = 0; mt < 4; ++mt)
#pragma unroll
        for (int nt = 0; nt < 4; ++nt)
          acc[mt][nt] = __builtin_amdgcn_mfma_f32_16x16x32_bf16(af[ks][mt], bfr[ks][nt],
                                                                acc[mt][nt], 0, 0, 0);
  }

  int q4 = lq * 4, ln = lm;
#pragma unroll
  for (int nt = 0; nt < 4; ++nt) {
    int c = n0 + wn * 64 + nt * 16 + ln;
    float bv = bias ? bias[c] : 0.f;
#pragma unroll
    for (int mt = 0; mt < 4; ++mt)
#pragma unroll
      for (int r = 0; r < 4; ++r)
        C[(size_t)(m0 + wm * 64 + mt * 16 + q4 + r) * 768 + c] = acc[mt][nt][r] + bv;
  }
}

// ---------------- 5. energy ----------------
__global__ __launch_bounds__(256) void energy_kernel(const float* __restrict__ dproj,
                                                     const float* __restrict__ eproj,
                                                     const float* vattn, const float* bv,
                                                     float* scores) {
  __shared__ float dch[16][65];
  __shared__ float ech[16][65];
  __shared__ float vch[64];
  int s0 = blockIdx.x * 16;
  int b  = blockIdx.y;
  int t0 = blockIdx.z * 16;
  int t = threadIdx.x;
  int sl = t & 15, tl = t >> 4;
  float acc = 0.f;
  for (int hc = 0; hc < 768; hc += 64) {
#pragma unroll
    for (int i = 0; i < 4; ++i) {
      int idx = i * 256 + t;
      int rr = idx >> 6, cc = idx & 63;
      dch[rr][cc] = dproj[(size_t)((t0 + rr) * 8 + b) * 768 + hc + cc];
      ech[rr][cc] = eproj[(size_t)((s0 + rr) * 8 + b) * 768 + hc + cc];
    }
    if (t < 64) vch[t] = vattn[hc + t];
    __syncthreads();
#pragma unroll 8
    for (int hh = 0; hh < 64; ++hh) {
      float x = dch[tl][hh] + ech[sl][hh];
      acc = fmaf(tanh_fast(x), vch[hh], acc);
    }
    __syncthreads();
  }
  scores[(size_t)((t0 + tl) * 8 + b) * 256 + s0 + sl] = acc + bv[0];
}

// ---------------- 6. masked softmax over s per row r ----------------
__global__ __launch_bounds__(256) void softmax_kernel(const float* scores, const int* sid, float* P) {
  __shared__ float red[256];
  int r = blockIdx.x, t = threadIdx.x, b = r & 7;
  float v = scores[(size_t)r * 256 + t];
  if (sid[t * 8 + b] == 0) v = -1e10f;
  red[t] = v;
  __syncthreads();
  for (int s = 128; s > 0; s >>= 1) {
    if (t < s) red[t] = fmaxf(red[t], red[t + s]);
    __syncthreads();
  }
  float m = red[0];
  __syncthreads();
  float e = __expf(v - m);
  red[t] = e;
  __syncthreads();
  for (int s = 128; s > 0; s >>= 1) {
    if (t < s) red[t] += red[t + s];
    __syncthreads();
  }
  P[(size_t)r * 256 + t] = e * (1.f / red[0]);
}

// ---------------- 7. ctx ----------------
__global__ __launch_bounds__(256) void ctx_kernel(const float* __restrict__ P,
                                                  const float* __restrict__ enc, float* ctx) {
  __shared__ float Pl[16][256];
  int h0 = blockIdx.x * 64;
  int b  = blockIdx.y;
  int tg = blockIdx.z;
  int t = threadIdx.x;
  int hl = t & 63, wv = t >> 6;
#pragma unroll
  for (int i = 0; i < 16; ++i) {
    int idx = i * 256 + t;
    int tt = idx >> 8, s = idx & 255;
    Pl[tt][s] = P[(size_t)((tg * 16 + tt) * 8 + b) * 256 + s];
  }
  __syncthreads();
  float acc[4] = {0.f, 0.f, 0.f, 0.f};
#pragma unroll 4
  for (int s = 0; s < 256; ++s) {
    float e = enc[(size_t)(s * 8 + b) * 768 + h0 + hl];
#pragma unroll
    for (int j = 0; j < 4; ++j)
      acc[j] = fmaf(Pl[wv * 4 + j][s], e, acc[j]);
  }
#pragma unroll
  for (int j = 0; j < 4; ++j)
    ctx[(size_t)((tg * 16 + wv * 4 + j) * 8 + b) * 768 + h0 + hl] = acc[j];
}

// ---------------- 8. p_gen ----------------
__global__ __launch_bounds__(256) void pgen_kernel(const float* dec, const float* ctx,
                                                   const float* tgt, const float* Wp,
                                                   const float* bp, float* pgen) {
  __shared__ float red[256];
  int r = blockIdx.x, t = threadIdx.x;
  float s = 0.f;
  for (int h = t; h < 768; h += 256) {
    s = fmaf(dec[(size_t)r * 768 + h], Wp[h], s);
    s = fmaf(ctx[(size_t)r * 768 + h], Wp[768 + h], s);
    s = fmaf(tgt[(size_t)r * 768 + h], Wp[1536 + h], s);
  }
  red[t] = s;
  __syncthreads();
  for (int st = 128; st > 0; st >>= 1) {
    if (t < st) red[t] += red[t + st];
    __syncthreads();
  }
  if (t == 0) pgen[r] = 1.f / (1.f + __expf(-(red[0] + bp[0])));
}

// ---------------- 9. vocab GEMM: depth-2 pipeline ----------
// Ring of 3 B-buffers staged 2 K-tiles ahead + register double-buffer for A staged
// 1 K-tile ahead. Per-phase FIFO: [T_kt(4), A_kt(8), T_kt+1(4), A_kt+1(8), T_kt+2(4)]
// -> vmcnt(16) drains exactly T_kt+A_kt (both issued >=1 full iteration earlier), so
// no wave ever waits on a load issued in its own phase. 12 fully peeled phases
// (compile-time constants; no runtime-indexed register arrays).
__global__ __launch_bounds__(256, 2) void gemm_vocab(const short* __restrict__ A,
                                                     const short* __restrict__ BT,
                                                     const float* __restrict__ bgen,
                                                     short* __restrict__ E,
                                                     float* __restrict__ prs) {
  __shared__ __align__(16) short Bl[3][128 * 64];   // 48KB
  int t = threadIdx.x;
  int w = t >> 6, l = t & 63;
  // bijective XCD swizzle: nwg=1572 = 8*196+4
  int orig = blockIdx.x;
  int xcd = orig & 7, ix = orig >> 3;
  int wgid = (xcd < 4 ? xcd * 197 : 788 + (xcd - 4) * 196) + ix;
  int nblk = wgid >> 2;
  int n0 = nblk * 128;
  int m0 = (wgid & 3) * 128;
  int wm = w >> 1, wn = w & 1;
  int lm = l & 15, lq = l >> 4;
  int srow = t >> 3;
  int scol = ((t & 7) ^ (srow & 7)) * 8;

  float4v acc[4][4];
#pragma unroll
  for (int i = 0; i < 4; ++i)
#pragma unroll
    for (int j = 0; j < 4; ++j) acc[i][j] = float4v{0.f, 0.f, 0.f, 0.f};

  const short* bS = BT + (size_t)(n0 + srow) * 768 + scol;
  const short* aR = A + (size_t)(m0 + wm * 64 + lm) * 768 + lq * 8;

  short8 afA[2][4], afB[2][4];

#define STAGE_V(buf, kt_)                                                      \
  {                                                                            \
    _Pragma("unroll")                                                          \
    for (int i_ = 0; i_ < 4; ++i_)                                             \
      gload16(bS + (size_t)i_ * 32 * 768 + (kt_) * 64,                         \
              &Bl[buf][(i_ * 32 + w * 8) * 64]);                               \
  }
#define LOADA_V(dst, kt_)                                                      \
  {                                                                            \
    _Pragma("unroll")                                                          \
    for (int ks_ = 0; ks_ < 2; ++ks_)                                          \
      _Pragma("unroll")                                                        \
      for (int mt_ = 0; mt_ < 4; ++mt_)                                        \
        dst[ks_][mt_] = *(const short8*)&aR[(size_t)mt_ * 16 * 768 +           \
                                            (kt_) * 64 + ks_ * 32];            \
  }
// PHASE kt: consume AFcur + Bl[kt%3]; prefetch A_{kt+1}->AFnxt, T_{kt+2}.
#define PHASE_V(kt, AFcur, AFnxt)                                              \
  {                                                                            \
    if ((kt) + 1 < 12) LOADA_V(AFnxt, (kt) + 1);                               \
    if ((kt) + 2 < 12) STAGE_V(((kt) + 2) % 3, (kt) + 2);                      \
    if ((kt) + 2 < 12)                                                         \
      asm volatile("s_waitcnt vmcnt(16)" ::: "memory");                        \
    else if ((kt) + 1 < 12)                                                    \
      asm volatile("s_waitcnt vmcnt(12)" ::: "memory");                        \
    else                                                                       \
      asm volatile("s_waitcnt vmcnt(0)" ::: "memory");                         \
    __builtin_amdgcn_s_barrier();                                              \
    __builtin_amdgcn_sched_barrier(0);                                         \
    short8 bfr[2][4];                                                          \
    _Pragma("unroll")                                                          \
    for (int ks_ = 0; ks_ < 2; ++ks_)                                          \
      _Pragma("unroll")                                                        \
      for (int nt_ = 0; nt_ < 4; ++nt_)                                        \
        bfr[ks_][nt_] = *(const short8*)&Bl[(kt) % 3]                          \
            [swz(wn * 64 + nt_ * 16 + lm, ks_ * 32 + lq * 8)];                 \
    asm volatile("s_waitcnt lgkmcnt(0)" ::: "memory");                         \
    __builtin_amdgcn_sched_barrier(0);                                         \
    __builtin_amdgcn_s_barrier();                                              \
    _Pragma("unroll")                                                          \
    for (int ks_ = 0; ks_ < 2; ++ks_)                                          \
      _Pragma("unroll")                                                        \
      for (int mt_ = 0; mt_ < 4; ++mt_)                                        \
        _Pragma("unroll")                                                      \
        for (int nt_ = 0; nt_ < 4; ++nt_)                                      \
          acc[mt_][nt_] = __builtin_amdgcn_mfma_f32_16x16x32_bf16(             \
              AFcur[ks_][mt_], bfr[ks_][nt_], acc[mt_][nt_], 0, 0, 0);         \
  }

  STAGE_V(0, 0);        // T0
  LOADA_V(afA, 0);      // A0
  STAGE_V(1, 1);        // T1   -> outstanding [T0(4), A0(8), T1(4)]

  PHASE_V(0, afA, afB)
  PHASE_V(1, afB, afA)
  PHASE_V(2, afA, afB)
  PHASE_V(3, afB, afA)
  PHASE_V(4, afA, afB)
  PHASE_V(5, afB, afA)
  PHASE_V(6, afA, afB)
  PHASE_V(7, afB, afA)
  PHASE_V(8, afA, afB)
  PHASE_V(9, afB, afA)
  PHASE_V(10, afA, afB)
  PHASE_V(11, afB, afA)

#undef PHASE_V
#undef LOADA_V
#undef STAGE_V

  // epilogue: exp, store bf16 (zeros in pad cols), per-row partial sums
  int q4 = lq * 4, ln = lm;
  float rs[4][4];
#pragma unroll
  for (int i = 0; i < 4; ++i)
#pragma unroll
    for (int j = 0; j < 4; ++j) rs[i][j] = 0.f;
#pragma unroll
  for (int nt = 0; nt < 4; ++nt) {
    int c = n0 + wn * 64 + nt * 16 + ln;
    bool valid = c < V_;
    float bg = valid ? bgen[c] : 0.f;
#pragma unroll
    for (int mt = 0; mt < 4; ++mt)
#pragma unroll
      for (int r = 0; r < 4; ++r) {
        float e = valid ? __expf(acc[mt][nt][r] + bg) : 0.f;
        int row = m0 + wm * 64 + mt * 16 + q4 + r;
        E[(size_t)row * VP_ + c] = f2bf(e);
        rs[mt][r] += e;
      }
  }
  // combine across lanes then across the 2 wn-waves via LDS (Bl[0] area, dead now:
  // last phases read Bl[2] (kt=11) and Bl[1] (kt=10); Bl[0] last read at kt=9, all
  // waves passed two barriers since).
  float* red = (float*)Bl;
  if (t < 128) red[t] = 0.f;
  __syncthreads();
#pragma unroll
  for (int mt = 0; mt < 4; ++mt)
#pragma unroll
    for (int r = 0; r < 4; ++r) {
      float v = rs[mt][r];
      v += __shfl_xor(v, 1);
      v += __shfl_xor(v, 2);
      v += __shfl_xor(v, 4);
      v += __shfl_xor(v, 8);
      if (ln == 0) atomicAdd(&red[wm * 64 + mt * 16 + q4 + r], v);
    }
  __syncthreads();
  if (t < 128) prs[(size_t)(m0 + t) * NBP_ + nblk] = red[t];
}

// ---------------- 9c. rowsums[r] = sum over nblk of prs[r][nblk] ----------------
__global__ __launch_bounds__(256) void rowsum_reduce(const float* __restrict__ prs,
                                                     float* __restrict__ rowsums) {
  __shared__ float red[256];
  int r = blockIdx.x, t = threadIdx.x;
  float s = prs[(size_t)r * NBP_ + t];
  if (t + 256 < NBLK_) s += prs[(size_t)r * NBP_ + t + 256];
  red[t] = s;
  __syncthreads();
  for (int st = 128; st > 0; st >>= 1) {
    if (t < st) red[t] += red[t + st];
    __syncthreads();
  }
  if (t == 0) rowsums[r] = red[0];
}

// ---------------- 10. final: out = E*pg/Z then scatter-add (chunk-local) ----------------
__global__ __launch_bounds__(256) void final_kernel(const short* __restrict__ E,
                                                    const float* __restrict__ P,
                                                    const float* pgen, const float* rowsums,
                                                    const int* sid, float* __restrict__ out) {
  int r = blockIdx.y, t = threadIdx.x, b = r & 7;
  int lo = blockIdx.x * 2048, hi = lo + 2048;
  float pg = pgen[r];
  float scale = pg / rowsums[r];
  const short* Er = E + (size_t)r * VP_;
  float* outr = out + (size_t)r * V_;
#pragma unroll
  for (int j = 0; j < 8; ++j) {
    int c = lo + j * 256 + t;
    if (c < V_) outr[c] = bf2f((unsigned short)Er[c]) * scale;
  }
  __syncthreads();
  int idx = sid[t * 8 + b];
  if (idx >= lo && idx < hi) {
    float ap = (1.f - pg) * P[(size_t)r * 256 + t];
    atomicAdd(&outr[idx], ap);
  }
}

extern "C" void kernel_launch(void* const* d_in, const int* in_sizes, int n_in,
                              void* d_out, int out_size, void* d_ws, size_t ws_size,
                              hipStream_t stream) {
  const float* enc  = (const float*)d_in[0];
  const float* dec  = (const float*)d_in[1];
  const int*   sid  = (const int*)d_in[2];
  const float* tgt  = (const float*)d_in[3];
  const float* Wat  = (const float*)d_in[4];
  const float* batt = (const float*)d_in[5];
  const float* vatt = (const float*)d_in[6];
  const float* bv   = (const float*)d_in[7];
  const float* Wp   = (const float*)d_in[8];
  const float* bp   = (const float*)d_in[9];
  const float* Wg   = (const float*)d_in[10];
  const float* bg   = (const float*)d_in[11];
  float* out = (float*)d_out;

  char* ws = (char*)d_ws;
  size_t off = 0;
  auto alloc = [&](size_t bytes) -> char* {
    char* p = ws + off;
    off += (bytes + 255) & ~(size_t)255;
    return p;
  };
  short* E16     = (short*)alloc((size_t)R_ * VP_ * 2);     // 51.5 MB
  short* WT16    = (short*)alloc((size_t)VP_ * H_ * 2);     // 77.3 MB
  short* dec16   = (short*)alloc((size_t)R_ * H_ * 2);
  short* enc16   = (short*)alloc((size_t)S_ * B_ * H_ * 2);
  short* WAT16   = (short*)alloc((size_t)H_ * 1536 * 2);
  float* dproj   = (float*)alloc((size_t)R_ * H_ * 4);
  float* eproj   = (float*)alloc((size_t)S_ * B_ * H_ * 4);
  float* scores  = (float*)alloc((size_t)R_ * 256 * 4);
  float* P       = (float*)alloc((size_t)R_ * 256 * 4);
  float* ctx     = (float*)alloc((size_t)R_ * H_ * 4);
  float* pgen    = (float*)alloc(R_ * 4);
  float* rowsums = (float*)alloc(R_ * 4);
  float* prs     = (float*)alloc((size_t)R_ * NBP_ * 4);    // 0.8 MB

  cvt_kernel<<<1920, 256, 0, stream>>>(dec, enc, dec16, enc16, rowsums);
  twat_kernel<<<dim3(12, 24), 256, 0, stream>>>(Wat, WAT16);
  cvt_wt_kernel<<<dim3(99, 24), 256, 0, stream>>>(Wg, WT16);
  gemm_proj<<<dim3(6, 4), 256, 0, stream>>>(dec16, WAT16, 0, nullptr, dproj);
  gemm_proj<<<dim3(6, 16), 256, 0, stream>>>(enc16, WAT16, 768, batt, eproj);
  energy_kernel<<<dim3(16, 8, 4), 256, 0, stream>>>(dproj, eproj, vatt, bv, scores);
  softmax_kernel<<<512, 256, 0, stream>>>(scores, sid, P);
  ctx_kernel<<<dim3(12, 8, 4), 256, 0, stream>>>(P, enc, ctx);
  pgen_kernel<<<512, 256, 0, stream>>>(dec, ctx, tgt, Wp, bp, pgen);
  gemm_vocab<<<dim3(1572), 256, 0, stream>>>(dec16, WT16, bg, E16, prs);
  rowsum_reduce<<<512, 256, 0, stream>>>(prs, rowsums);
  final_kernel<<<dim3(25, 512), 256, 0, stream>>>(E16, P, pgen, rowsums, sid, out);
}